// Round 4
// baseline (214.088 us; speedup 1.0000x reference)
//
#include <hip/hip_runtime.h>
#include <stdint.h>

// Shapes fixed by the reference setup_inputs()
#define B 8
#define N 256
#define D 256
#define O 256
#define R 512
#define E 8192
#define TR 4
#define TRO 8
#define NSW 8192              // persistent sample waves (2048 blocks x 4)
#define F32_TINY 1.17549435e-38f

// ---------------- threefry2x32, key = (0, 42) --------------------------------
__device__ __forceinline__ void threefry2x32_k42(uint32_t x0, uint32_t x1,
                                                 uint32_t& o0, uint32_t& o1) {
  const uint32_t ks0 = 0u;
  const uint32_t ks1 = 42u;
  const uint32_t ks2 = 0u ^ 42u ^ 0x1BD11BDAu;
  x0 += ks0; x1 += ks1;
#define TF_R(r) { x0 += x1; x1 = (x1 << (r)) | (x1 >> (32 - (r))); x1 ^= x0; }
  TF_R(13) TF_R(15) TF_R(26) TF_R(6)
  x0 += ks1; x1 += ks2 + 1u;
  TF_R(17) TF_R(29) TF_R(16) TF_R(24)
  x0 += ks2; x1 += ks0 + 2u;
  TF_R(13) TF_R(15) TF_R(26) TF_R(6)
  x0 += ks0; x1 += ks1 + 3u;
  TF_R(17) TF_R(29) TF_R(16) TF_R(24)
  x0 += ks1; x1 += ks2 + 4u;
  TF_R(13) TF_R(15) TF_R(26) TF_R(6)
  x0 += ks2; x1 += ks0 + 5u;
#undef TF_R
  o0 = x0; o1 = x1;
}

__device__ __forceinline__ float gumbel_from_bits_f(float f) {
  float u = (f == 0.0f) ? F32_TINY : f;
  return -logf(-logf(u));
}

// ---------------- prep: transpose(score,f2e) + Wr GEMM + wcount=0 ------------
__global__ __launch_bounds__(256) void prep_kernel(const float* __restrict__ score,
                                                   float* __restrict__ scoreT,
                                                   const float* __restrict__ f2e,
                                                   float* __restrict__ f2eT,
                                                   const float* __restrict__ relf,
                                                   const float* __restrict__ Wk,
                                                   const float* __restrict__ bk,
                                                   float* __restrict__ Wr,
                                                   int* __restrict__ wcount) {
  int blk = blockIdx.x;
  if (blk == 0 && threadIdx.x == 0) *wcount = 0;
  if (blk < 256) {
    __shared__ float tile[64][65];
    const float* src = (blk < 128) ? score : f2e;
    float* dst = (blk < 128) ? scoreT : f2eT;
    int b7 = blk & 127;
    int bb = b7 >> 4, t = b7 & 15, ti = t >> 2, tj = t & 3;
    size_t base = (size_t)bb * 65536;
    int c = threadIdx.x & 63, r4 = threadIdx.x >> 6;
#pragma unroll
    for (int rr = 0; rr < 64; rr += 4) {
      int row = rr + r4;
      tile[row][c] = src[base + (size_t)(ti * 64 + row) * 256 + tj * 64 + c];
    }
    __syncthreads();
#pragma unroll
    for (int rr = 0; rr < 64; rr += 4) {
      int row = rr + r4;
      dst[base + (size_t)(tj * 64 + row) * 256 + ti * 64 + c] = tile[c][row];
    }
  } else {
    __shared__ float rrow[TR][D];
    int r0 = (blk - 256) * TR;
    int o = threadIdx.x;
#pragma unroll
    for (int r = 0; r < TR; ++r) rrow[r][o] = relf[(size_t)(r0 + r) * D + o];
    __syncthreads();
    double acc[TR] = {0, 0, 0, 0};
    for (int d = 0; d < D; d += 4) {
      float w0 = Wk[(size_t)(d + 0) * O + o];
      float w1 = Wk[(size_t)(d + 1) * O + o];
      float w2 = Wk[(size_t)(d + 2) * O + o];
      float w3 = Wk[(size_t)(d + 3) * O + o];
#pragma unroll
      for (int r = 0; r < TR; ++r) {
        float4 a = *(const float4*)&rrow[r][d];
        acc[r] += (double)a.x * w0; acc[r] += (double)a.y * w1;
        acc[r] += (double)a.z * w2; acc[r] += (double)a.w * w3;
      }
    }
    float bv = bk[o];
#pragma unroll
    for (int r = 0; r < TR; ++r) Wr[(size_t)(r0 + r) * O + o] = (float)acc[r] + bv;
  }
}

// ---------------- fused sim + logits + laux + cand + worklist ----------------
__global__ __launch_bounds__(256) void simcand_kernel(const float* __restrict__ f2e,
                                                      const float* __restrict__ f2eT,
                                                      const float* __restrict__ scoreT,
                                                      const int* __restrict__ edge,
                                                      const int* __restrict__ epsp,
                                                      float* __restrict__ logits,
                                                      float* __restrict__ laux,
                                                      int* __restrict__ wlist,
                                                      int* __restrict__ wcount) {
  int bn0 = blockIdx.x * TR;    // 4 consecutive (b,n) rows, same b
  int b = bn0 >> 8;
  int tid = threadIdx.x, lane = tid & 63, w = tid >> 6;
  __shared__ float arow[TR][256];   // f2e rows, later reused for sim rows
  __shared__ float nbuf[TR][256];
  __shared__ float x2s[256];
#pragma unroll
  for (int r = 0; r < TR; ++r) arow[r][tid] = f2e[(size_t)(bn0 + r) * 256 + tid];
  __syncthreads();
  // dot(f2e[row], f2e[b,col]) + column x2, both ascending-d f64 chains
  double acc[TR] = {0, 0, 0, 0};
  double ax2 = 0.0;
  const float* fT = f2eT + (size_t)b * 65536 + tid;
  for (int dd = 0; dd < 256; dd += 4) {
    float b0 = fT[(size_t)(dd + 0) * 256];
    float b1 = fT[(size_t)(dd + 1) * 256];
    float b2 = fT[(size_t)(dd + 2) * 256];
    float b3 = fT[(size_t)(dd + 3) * 256];
    ax2 += (double)b0 * b0; ax2 += (double)b1 * b1;
    ax2 += (double)b2 * b2; ax2 += (double)b3 * b3;
#pragma unroll
    for (int r = 0; r < TR; ++r) {
      float4 a = *(const float4*)&arow[r][dd];
      acc[r] += (double)a.x * b0; acc[r] += (double)a.y * b1;
      acc[r] += (double)a.z * b2; acc[r] += (double)a.w * b3;
    }
  }
  float x2c = (float)ax2;
  x2s[tid] = x2c;
  __syncthreads();
#pragma unroll
  for (int r = 0; r < TR; ++r) {
    float x2r = x2s[(bn0 + r) & 255];
    float d2 = (x2r + x2c) - 2.0f * (float)acc[r];  // ==0 exactly at diag
    nbuf[r][tid] = -sqrtf(fmaxf(d2, 0.0f));
  }
  __syncthreads();
  // wave w owns row bn0+w: softmax + logits + laux; sim row -> arow[w][*]
  {
    float v0 = nbuf[w][lane], v1 = nbuf[w][lane + 64],
          v2 = nbuf[w][lane + 128], v3 = nbuf[w][lane + 192];
    float mx = fmaxf(fmaxf(v0, v1), fmaxf(v2, v3));
#pragma unroll
    for (int off = 32; off > 0; off >>= 1) mx = fmaxf(mx, __shfl_xor(mx, off));
    float p0 = expf(v0 - mx), p1 = expf(v1 - mx), p2 = expf(v2 - mx), p3 = expf(v3 - mx);
    double sd = (double)p0 + (double)p1 + (double)p2 + (double)p3;
#pragma unroll
    for (int off = 32; off > 0; off >>= 1) sd += __shfl_xor(sd, off);
    float denom = (float)sd;
    float s0 = p0 / denom, s1 = p1 / denom, s2 = p2 / denom, s3 = p3 / denom;
    arow[w][lane] = s0; arow[w][lane + 64] = s1;
    arow[w][lane + 128] = s2; arow[w][lane + 192] = s3;
    float l0 = logf(s0), l1 = logf(s1), l2 = logf(s2), l3 = logf(s3);
    size_t rb = (size_t)(bn0 + w) * 256;
    logits[rb + lane] = l0; logits[rb + lane + 64] = l1;
    logits[rb + lane + 128] = l2; logits[rb + lane + 192] = l3;
    int dm = (bn0 + w) & 255;
    int dj = dm >> 6, dl = dm & 63;
    float e0 = (dj == 0 && lane == dl) ? -3.4e38f : l0;
    float e1 = (dj == 1 && lane == dl) ? -3.4e38f : l1;
    float e2 = (dj == 2 && lane == dl) ? -3.4e38f : l2;
    float e3 = (dj == 3 && lane == dl) ? -3.4e38f : l3;
    float Lm = fmaxf(fmaxf(e0, e1), fmaxf(e2, e3));
#pragma unroll
    for (int off = 32; off > 0; off >>= 1) Lm = fmaxf(Lm, __shfl_xor(Lm, off));
    float lown = (dj == 0) ? l0 : (dj == 1) ? l1 : (dj == 2) ? l2 : l3;
    float l_n = __shfl(lown, dl);
    if (lane == 0) {
      laux[2 * (bn0 + w) + 0] = l_n;
      laux[2 * (bn0 + w) + 1] = Lm;
    }
  }
  __syncthreads();
  // cand = (sim @ score^T > eps) & (edge < 1), push active rows to worklist
  double acc2[TR] = {0, 0, 0, 0};
  const float* sT = scoreT + (size_t)b * 65536 + tid;
  for (int kk = 0; kk < 256; kk += 4) {
    float b0 = sT[(size_t)(kk + 0) * 256];
    float b1 = sT[(size_t)(kk + 1) * 256];
    float b2 = sT[(size_t)(kk + 2) * 256];
    float b3 = sT[(size_t)(kk + 3) * 256];
#pragma unroll
    for (int r = 0; r < TR; ++r) {
      float4 a = *(const float4*)&arow[r][kk];
      acc2[r] += (double)a.x * b0; acc2[r] += (double)a.y * b1;
      acc2[r] += (double)a.z * b2; acc2[r] += (double)a.w * b3;
    }
  }
  float epsv = (float)epsp[0];
#pragma unroll
  for (int r = 0; r < TR; ++r) {
    int row = (bn0 + r) * 256 + tid;
    int em = edge[(size_t)row];
    bool active = ((float)acc2[r] > epsv) && (em < 1);
    unsigned long long mask = __ballot(active);
    int cnt = __popcll(mask);
    int basev = 0;
    if (lane == 0 && cnt) basev = atomicAdd(wcount, cnt);
    basev = __shfl(basev, 0);
    if (active) {
      int pos = basev + __popcll(mask & ((1ull << lane) - 1ull));
      wlist[pos] = row;
    }
  }
}

// ---------------- sampling over compacted worklist + batch scatter -----------
__global__ __launch_bounds__(256) void sample_kernel(const float* __restrict__ logits,
                                                     const float* __restrict__ laux,
                                                     const int* __restrict__ wlist,
                                                     const int* __restrict__ wcount,
                                                     const int* __restrict__ edge,
                                                     const int* __restrict__ heads,
                                                     const int* __restrict__ rels,
                                                     const int* __restrict__ tails,
                                                     float* __restrict__ counts) {
  int blk = blockIdx.x;
  if (blk >= 2048) {
    // batch head/tail incidence
    int i = (blk - 2048) * 256 + threadIdx.x;  // [0, B*E)
    int b = i >> 13;                            // E = 8192
    int h = heads[i], r = rels[i], t = tails[i];
    atomicAdd(&counts[(size_t)(b * N + h) * R + r], 1.0f);
    atomicAdd(&counts[(size_t)(b * N + t) * R + r], 1.0f);
    return;
  }
  int lane = threadIdx.x & 63;
  int gw = blk * 4 + (threadIdx.x >> 6);
  int cnt = *wcount;
  for (int idx = gw; idx < cnt; idx += NSW) {
    int row = wlist[idx];
    int b = row >> 16;
    int n = (row >> 8) & 255;
    int c = row & 255;
    uint32_t base = (uint32_t)row << 8;
    float u0, u1, u2, u3;
    {
      uint32_t a0, a1;
#define GEN_U(q, dst)                                                     \
      threefry2x32_k42(0u, base + (uint32_t)((q) * 64 + lane), a0, a1);    \
      dst = __uint_as_float((((a0 ^ a1) >> 9)) | 0x3f800000u) - 1.0f;
      GEN_U(0, u0) GEN_U(1, u1) GEN_U(2, u2) GEN_U(3, u3)
#undef GEN_U
    }
    float l_n  = laux[2 * ((b << 8) + n) + 0];
    float Lmax = laux[2 * ((b << 8) + n) + 1];
    int qo = n >> 6;
    float uo = (qo == 0) ? u0 : (qo == 1) ? u1 : (qo == 2) ? u2 : u3;
    float u_n = __shfl(uo, n & 63);
    float v_n = gumbel_from_bits_f(u_n) + l_n;
    // conservative screen: u <= u_thr => g + l_k <= v_n - 0.125 + eps < v_n
    float thr_g = (v_n - Lmax) - 0.125f;
    float u_thr = expf(-expf(-thr_g));
    bool owner = (lane == (n & 63));
    bool anyc = ((u0 > u_thr) && !(owner && qo == 0)) |
                ((u1 > u_thr) && !(owner && qo == 1)) |
                ((u2 > u_thr) && !(owner && qo == 2)) |
                ((u3 > u_thr) && !(owner && qo == 3));
    if (!__any(anyc)) continue;            // argmax = n -> new_rel = 0 -> nothing

    // ---- slow path (rare): exact full argmax ----
    const float* lrow = logits + (size_t)((b << 8) + n) * N;
    float bestv = -1e30f;
    int besti = 0;
    for (int q = 0; q < 4; ++q) {
      int k = q * 64 + lane;
      uint32_t o0, o1;
      threefry2x32_k42(0u, base + (uint32_t)k, o0, o1);
      uint32_t bits = o0 ^ o1;
      float f = __uint_as_float((bits >> 9) | 0x3f800000u) - 1.0f;
      float g = gumbel_from_bits_f(f);
      float v = g + lrow[k];
      if (v > bestv || (v == bestv && k < besti)) { bestv = v; besti = k; }
    }
    for (int off = 32; off > 0; off >>= 1) {
      float ov = __shfl_down(bestv, off);
      int oi = __shfl_down(besti, off);
      if (ov > bestv || (ov == bestv && oi < besti)) { bestv = ov; besti = oi; }
    }
    if (lane == 0) {
      int nr = edge[(size_t)((b << 8) + besti) * N + c];
      if (nr != 0) {
        atomicAdd(&counts[(size_t)((b << 8) + n) * R + nr], 1.0f);
        atomicAdd(&counts[(size_t)((b << 8) + c) * R + nr], 1.0f);
      }
    }
  }
}

// ---------------- out = relu(counts @ Wr), 8 rows/block, f32 acc -------------
__global__ __launch_bounds__(256) void out_kernel(const float* __restrict__ counts,
                                                  const float* __restrict__ Wr,
                                                  float* __restrict__ out) {
  int bn0 = blockIdx.x * TRO;
  int o = threadIdx.x;
  __shared__ float crow[TRO][R];
#pragma unroll
  for (int r = 0; r < TRO; ++r) {
    crow[r][o] = counts[(size_t)(bn0 + r) * R + o];
    crow[r][o + 256] = counts[(size_t)(bn0 + r) * R + 256 + o];
  }
  __syncthreads();
  float acc[TRO] = {0, 0, 0, 0, 0, 0, 0, 0};
  for (int k = 0; k < R; k += 4) {
    float w0 = Wr[(size_t)(k + 0) * O + o];
    float w1 = Wr[(size_t)(k + 1) * O + o];
    float w2 = Wr[(size_t)(k + 2) * O + o];
    float w3 = Wr[(size_t)(k + 3) * O + o];
#pragma unroll
    for (int r = 0; r < TRO; ++r) {
      float4 cv = *(const float4*)&crow[r][k];
      acc[r] += cv.x * w0; acc[r] += cv.y * w1;
      acc[r] += cv.z * w2; acc[r] += cv.w * w3;
    }
  }
#pragma unroll
  for (int r = 0; r < TRO; ++r)
    out[(size_t)(bn0 + r) * O + o] = fmaxf(acc[r], 0.0f);
}

extern "C" void kernel_launch(void* const* d_in, const int* in_sizes, int n_in,
                              void* d_out, int out_size, void* d_ws, size_t ws_size,
                              hipStream_t stream) {
  (void)in_sizes; (void)n_in; (void)out_size; (void)ws_size;
  const float* f2e   = (const float*)d_in[0];
  const float* score = (const float*)d_in[1];
  const float* relf  = (const float*)d_in[2];
  const float* Wk    = (const float*)d_in[3];
  const float* bk    = (const float*)d_in[4];
  // d_in[5] local_entity: unused by the reference computation
  const int* heads   = (const int*)d_in[6];
  const int* rels    = (const int*)d_in[7];
  const int* tails   = (const int*)d_in[8];
  const int* edge    = (const int*)d_in[9];
  const int* epsp    = (const int*)d_in[10];
  float* out = (float*)d_out;

  // workspace (floats): logits | Wr | counts(4MB; scoreT+f2eT alias it) |
  //                     laux | wlist | wcount
  float* ws     = (float*)d_ws;
  float* logits = ws;
  float* Wr     = logits + 524288;
  float* counts = Wr + 131072;
  float* scoreT = counts;                       // alias, dead after simcand
  float* f2eT   = counts + 524288;              // alias, dead after simcand
  float* laux   = counts + 1048576;
  int*   wlist  = (int*)(laux + 4096);
  int*   wcount = wlist + 524288;

  prep_kernel<<<384, 256, 0, stream>>>(score, scoreT, f2e, f2eT,
                                       relf, Wk, bk, Wr, wcount);
  simcand_kernel<<<(B * N) / TR, 256, 0, stream>>>(f2e, f2eT, scoreT, edge, epsp,
                                                   logits, laux, wlist, wcount);
  hipMemsetAsync(counts, 0, (size_t)B * N * R * sizeof(float), stream);
  sample_kernel<<<2048 + 256, 256, 0, stream>>>(logits, laux, wlist, wcount, edge,
                                                heads, rels, tails, counts);
  out_kernel<<<(B * N) / TRO, 256, 0, stream>>>(counts, Wr, out);
}